// Round 9
// baseline (10490.073 us; speedup 1.0000x reference)
//
#include <hip/hip_runtime.h>
#include <stdint.h>

// Problem: D-FPS. points_xyz (16, 131072, 3) fp32 -> indices (16, 4096) int32.
//
// Round 9 = round 8 (all-relaxed single-word protocol; 2.1x best) plus
// critical-path shaving:
//  - w0 prefetches all 16 candidate coords during the global poll; winner
//    coords delivered by shuffle (no dependent bxyz load).
//  - bc broadcast carries coords; workgroup-scope release/acquire only
//    (s_waitcnt lgkmcnt, no cache maintenance). Followers never touch bxyz.
//  - 4-step final butterfly (lanes 0..15 are a full 16-hypercube) + ballot.
//  - software-pipelined global poll (next load in flight while testing).
//  - s_sleep in the follower bc-spin (issue-pressure relief for w0).
// r2-r7 lessons baked in: relaxed-only agent atomics (acquire/release at
// agent scope = chip-wide cache-maintenance storms); ONE polling wave per
// block; points in LDS (allocator refuses register residency); FMA-chain
// distance d = fma(dz,dz, fma(dy,dy, dx*dx)) with exact-rounded subs.

#define BATCH 16
#define NPTS  131072
#define NSAMP 4096
#define NBLK  16                  // blocks per batch
#define TPB   1024                // 16 waves
#define CHUNK (NPTS / NBLK)       // 8192 points per block
#define PPT   (CHUNK / TPB)       // 8 points per thread
#define NWAVE (TPB / 64)

typedef unsigned long long u64;
typedef unsigned int u32;

// Global slot word (8B, one per block per parity):
//   [63:32] dist bits (>=0 -> monotone) | [31:15] idx (17b) | [14:0] iter tag
// Poison 0xAA.. -> tag 0x2AAA; zero-init -> tag 0; live tags are 1..4095.
// Ring-2 by parity; ordering holds via the value-dependence chain (r8-proven).

__global__ void fps_init_kernel(u64* __restrict__ ws) {
    int i = blockIdx.x * blockDim.x + threadIdx.x;
    if (i < BATCH * 2 * NBLK) ws[i] = 0ull;
}

__global__ __launch_bounds__(TPB, 4) void fps_kernel(
        const float* __restrict__ xyz, int* __restrict__ out,
        u64* __restrict__ gslot) {
    const int blk   = blockIdx.x;
    const int b     = blk & 15;    // batch: a batch's 16 blocks have constant
    const int chunk = blk >> 4;    // blk%8 -> same XCD (round-robin heuristic)
    const int tid   = threadIdx.x;
    const int w     = tid >> 6;
    const int lane  = tid & 63;

    const float* bxyz = xyz + (size_t)b * NPTS * 3;
    const int base = chunk * CHUNK;

    // ---- LDS: SoA points + sync words ----
    __shared__ float2 sxy[CHUNK];          // 64 KB
    __shared__ float  szz[CHUNK];          // 32 KB
    __shared__ u64 red[2][NWAVE];          // 256 B
    __shared__ u64 bcA[2], bcB[2];         // 32 B
    for (int i = tid; i < CHUNK; i += TPB) {
        size_t p = (size_t)(base + i) * 3;
        sxy[i] = make_float2(bxyz[p + 0], bxyz[p + 1]);
        szz[i] = bxyz[p + 2];
    }
    if (tid < 2 * NWAVE) ((u64*)red)[tid] = ~0ull;  // tag 0x7FFF: invalid
    if (tid < 2) { bcA[tid] = ~0ull; bcB[tid] = ~0ull; }  // low32 invalid
    if (tid == 0 && chunk == 0) out[b * NSAMP] = 0; // iter 0 emits index 0
    __syncthreads();   // staging visibility (only block-wide barrier)

    float pd[PPT];
#pragma unroll
    for (int k = 0; k < PPT; ++k) pd[k] = __builtin_inff();

    float cx = bxyz[0], cy = bxyz[1], cz = bxyz[2];

    u64* gs = gslot + (size_t)b * 2 * NBLK;   // [2][NBLK]

    for (int it = 1; it < NSAMP; ++it) {
        const int par = it & 1;
        u64* gsp = gs + par * NBLK;

        // ---- update min-dists + local argmax (LDS + registers) ----
        // Verified arithmetic (round 2, absmax 0): FMA-contracted
        //   d = fma(dz,dz, fma(dy,dy, dx*dx)), subs exact-rounded.
        float bd = -1.0f;
        int   bk = 0;
#pragma unroll
        for (int k = 0; k < PPT; ++k) {
            int i = tid + TPB * k;
            float2 xy = sxy[i];
            float  z  = szz[i];
            float dx = __fsub_rn(xy.x, cx);
            float dy = __fsub_rn(xy.y, cy);
            float dz = __fsub_rn(z,    cz);
            float d  = __builtin_fmaf(dz, dz,
                         __builtin_fmaf(dy, dy, __fmul_rn(dx, dx)));
            float nd = fminf(pd[k], d);
            pd[k] = nd;
            // strict >: earliest k wins (gi ascends with k) = first-occurrence
            if (nd > bd) { bd = nd; bk = k; }
        }
        u32 gi = (u32)(base + tid + TPB * bk);
        u64 key = ((u64)__float_as_uint(bd) << 32) | (u64)(~gi);

        // ---- wave butterfly (max dist, then min index) ----
#pragma unroll
        for (int off = 1; off <= 32; off <<= 1) {
            u64 o = __shfl_xor(key, off, 64);
            key = key > o ? key : o;
        }
        if (lane == 0) {
            u32 db  = (u32)(key >> 32);
            u32 idx = ~(u32)key;          // = gi (fits 17 bits)
            __hip_atomic_store(&red[par][w],
                               ((u64)db << 32) | ((u64)idx << 15) | (u64)it,
                               __ATOMIC_RELAXED, __HIP_MEMORY_SCOPE_WORKGROUP);
        }

        if (w == 0) {
            // ---- combine the 16 wave entries from LDS ----
            u64 v; bool ok;
            do {
                v  = (lane < NWAVE)
                       ? __hip_atomic_load(&red[par][lane], __ATOMIC_RELAXED,
                                           __HIP_MEMORY_SCOPE_WORKGROUP)
                       : 0ull;
                ok = (lane < NWAVE) ? ((v & 0x7FFFull) == (u64)it) : true;
            } while (__ballot(ok) != ~0ull);
            u64 k2 = 0ull;
            if (lane < NWAVE) {
                u32 db  = (u32)(v >> 32);
                u32 idx = (u32)((v >> 15) & 0x1FFFFu);
                k2 = ((u64)db << 32) | (u64)(~idx);
            }
#pragma unroll
            for (int off = 1; off <= 8; off <<= 1) {
                u64 o = __shfl_xor(k2, off, 64);
                k2 = k2 > o ? k2 : o;
            }
            // ---- ONE relaxed agent store publishes the block winner ----
            if (lane == 0) {
                u32 db  = (u32)(k2 >> 32);
                u32 idx = ~(u32)k2;
                __hip_atomic_store(&gsp[chunk],
                                   ((u64)db << 32) | ((u64)idx << 15) | (u64)it,
                                   __ATOMIC_RELAXED, __HIP_MEMORY_SCOPE_AGENT);
            }
            // ---- software-pipelined relaxed poll of the 16 slot words ----
            v = (lane < NBLK)
                    ? __hip_atomic_load(&gsp[lane], __ATOMIC_RELAXED,
                                        __HIP_MEMORY_SCOPE_AGENT)
                    : 0ull;
            for (;;) {
                u64 nxt = (lane < NBLK)
                              ? __hip_atomic_load(&gsp[lane], __ATOMIC_RELAXED,
                                                  __HIP_MEMORY_SCOPE_AGENT)
                              : 0ull;
                ok = (lane < NBLK) ? ((v & 0x7FFFull) == (u64)it) : true;
                if (__ballot(ok) == ~0ull) break;
                v = nxt;
            }
            // Prefetch ALL 16 candidates' coords now; loads overlap the
            // butterfly below; winner coords arrive via 3 shuffles.
            u32 ci = (lane < NBLK) ? (u32)((v >> 15) & 0x1FFFFu) : 0u;
            float fx = bxyz[3 * (size_t)ci + 0];
            float fy = bxyz[3 * (size_t)ci + 1];
            float fz = bxyz[3 * (size_t)ci + 2];

            u64 k3o = 0ull;
            if (lane < NBLK) {
                u32 db = (u32)(v >> 32);
                k3o = ((u64)db << 32) | (u64)(~ci);
            }
            u64 k3 = k3o;
#pragma unroll
            for (int off = 1; off <= 8; off <<= 1) {  // lanes 0..15: full combine
                u64 o = __shfl_xor(k3, off, 64);
                k3 = k3 > o ? k3 : o;
            }
            // winner lane: candidates are distinct -> exactly one match
            u64 mine = __ballot((lane < NBLK) && (k3o == k3));
            int wl = (int)__builtin_ctzll(mine);
            cx = __shfl(fx, wl, 64);
            cy = __shfl(fy, wl, 64);
            cz = __shfl(fz, wl, 64);
            u32 widx = __shfl(ci, wl, 64);

            if (lane == 0) {
                if (chunk == 0) out[b * NSAMP + it] = (int)widx;
                // coords ride the broadcast: payload relaxed, tag word
                // RELEASE at WORKGROUP scope (= lgkmcnt wait only, no cache
                // ops — the r7 disaster was AGENT-scope release).
                __hip_atomic_store(&bcA[par],
                    ((u64)__float_as_uint(cx) << 32) | (u64)__float_as_uint(cy),
                    __ATOMIC_RELAXED, __HIP_MEMORY_SCOPE_WORKGROUP);
                __hip_atomic_store(&bcB[par],
                    ((u64)__float_as_uint(cz) << 32) | (u64)(u32)it,
                    __ATOMIC_RELEASE, __HIP_MEMORY_SCOPE_WORKGROUP);
            }
        } else {
            // ---- other waves: wait for tagged LDS broadcast (coords inside) --
            u64 bv = __hip_atomic_load(&bcB[par], __ATOMIC_ACQUIRE,
                                       __HIP_MEMORY_SCOPE_WORKGROUP);
            while ((u32)bv != (u32)it) {
                __builtin_amdgcn_s_sleep(1);
                bv = __hip_atomic_load(&bcB[par], __ATOMIC_ACQUIRE,
                                       __HIP_MEMORY_SCOPE_WORKGROUP);
            }
            u64 av = __hip_atomic_load(&bcA[par], __ATOMIC_RELAXED,
                                       __HIP_MEMORY_SCOPE_WORKGROUP);
            cz = __uint_as_float((u32)(bv >> 32));
            cx = __uint_as_float((u32)(av >> 32));
            cy = __uint_as_float((u32)av);
        }
    }
}

extern "C" void kernel_launch(void* const* d_in, const int* in_sizes, int n_in,
                              void* d_out, int out_size, void* d_ws, size_t ws_size,
                              hipStream_t stream) {
    const float* xyz = (const float*)d_in[0];
    int* out = (int*)d_out;
    u64* gslot = (u64*)d_ws;   // [BATCH][2][NBLK] u64 = 4 KB

    hipLaunchKernelGGL(fps_init_kernel, dim3(1), dim3(512), 0, stream, gslot);
    hipLaunchKernelGGL(fps_kernel, dim3(BATCH * NBLK), dim3(TPB), 0, stream,
                       xyz, out, gslot);
}